// Round 4
// baseline (567.119 us; speedup 1.0000x reference)
//
#include <hip/hip_runtime.h>

// Problem geometry (fixed by reference):
//   x: (2, 32, 96,96,96) fp32; W: (1024,1024) fp32 [o][k]; bias: (1024,)
//   P=4 -> T=64, Q = 24^3 = 13824, spatial s = t*Q + q
//   GEMM: M=55296 (b,g,q), K=1024 (k=j*32+c), N=1024 (o)
//   A[m,k] = x[b][c][t_src*Q + q],  t_src = (32g + j + 48) & 63  (j = k>>5, c = k&31)
//   out[b][o&31][tt*Q + q] = Y[m,o] + bias[o],  tt = (32g + (o>>5) + 48) & 63
//
// V4: V3 showed GEMM is NOT memory-bound (8% HBM) — it pays a 16-way LDS read
// conflict (4.2e7) and the A-prepass costs ~115us of pure HBM round-trip.
//   - A-prepass ELIMINATED: conversion fused into the GEMM via reg-staging
//     (8 coalesced f32x4 plane-loads/thread -> cvt -> ds_write_b128). Since A
//     is ds_write-staged (not global_load_lds), its LDS image is XOR-swizzled:
//     byte ^= (row&7)<<4 on both write and read -> read conflicts ~16-way -> ~2.
//   - Wbf tile layout PRE-swizzled in the (tiny, 2MB) W prepass; GEMM copies it
//     linearly with global_load_lds (dest must stay linear) and reads with the
//     same XOR -> B reads de-conflicted too (HK s09 pre-swizzled-source pattern).
//   - Same 2-barrier loop / epilogue / XCD-grouping swizzle as passing V3;
//     identical f2bf + MFMA order -> bit-identical output.

#define NSPAT 884736   // 96^3
#define QQ    13824    // 24^3
#define MTOT  55296
#define KK    1024
#define TS    8192     // shorts per 128x64 tile (16 KB)

typedef __attribute__((ext_vector_type(4))) float f32x4;
typedef __attribute__((ext_vector_type(8))) short bf16x8;

__device__ __forceinline__ short f2bf(float f) {
  // round-to-nearest-even fp32 -> bf16 (inputs finite)
  unsigned u = __builtin_bit_cast(unsigned, f);
  u += 0x7fff + ((u >> 16) & 1);
  return (short)(u >> 16);
}

__device__ __forceinline__ void async16(short* lds, const short* g) {
  // global -> LDS direct copy, 16 B per lane; LDS dest = wave-uniform base + lane*16
  __builtin_amdgcn_global_load_lds(
      (const __attribute__((address_space(1))) unsigned*)g,
      (__attribute__((address_space(3))) unsigned*)lds, 16, 0, 0);
}

// ---------------------------------------------------------------------------
// K1: build Wbf (bf16) as 128x64 tiles in PRE-SWIZZLED LDS image order:
// tile (nt*16+kt); element (row, k-octet oc) stored at
//   row*64 + ((oc*8) ^ ((row&7)<<3))   [shorts]
// so a linear global_load_lds copy lands the swizzled image in LDS.
// ---------------------------------------------------------------------------
__global__ __launch_bounds__(256)
void convert_w(const float* __restrict__ Wm, short* __restrict__ Wbf) {
  const int wb = blockIdx.x;      // nt*16 + kt, 128 blocks
  const int tid = threadIdx.x;
  const int nt = wb >> 4;
  const int kt = wb & 15;
  const int n0 = nt * 128;
#pragma unroll
  for (int it = 0; it < 4; it++) {
    const int idx = it * 256 + tid;   // octet index in tile
    const int row = idx >> 3;
    const int oc  = idx & 7;
    const float* wsrc = Wm + (size_t)(n0 + row) * 1024 + kt * 64 + oc * 8;
    const f32x4 a = *(const f32x4*)(wsrc);
    const f32x4 b = *(const f32x4*)(wsrc + 4);
    bf16x8 f;
#pragma unroll
    for (int t = 0; t < 4; t++) { f[t] = f2bf(a[t]); f[t + 4] = f2bf(b[t]); }
    const int swz = (oc * 8) ^ ((row & 7) << 3);
    *(bf16x8*)(Wbf + (size_t)wb * TS + row * 64 + swz) = f;
  }
}

// ---------------------------------------------------------------------------
// K2: fused convert+GEMM. Tile 128x128, BK=64, 4 waves (2x2 of 64x64),
// 2-barrier loop. A: reg-staged from x (fp32, coalesced plane reads) -> cvt ->
// swizzled ds_write. B: global_load_lds from pre-swizzled Wbf tiles.
// ---------------------------------------------------------------------------
__global__ __launch_bounds__(256, 2)
void swin_fused(const float* __restrict__ x, const short* __restrict__ Bw,
                const float* __restrict__ bias, float* __restrict__ out) {
  __shared__ __align__(16) short As[128 * 64];
  __shared__ __align__(16) short Bs[128 * 64];

  // XCD-grouping swizzle: grid 3456 = 8 xcd * 432 (bijective since 8 | 3456).
  const int b0 = blockIdx.x;
  const int logical = (b0 & 7) * 432 + (b0 >> 3);
  const int nt = logical & 7;     // n fastest: siblings share the x panel in L2
  const int mt = logical >> 3;
  const int seg = mt / 108;
  const int q0  = (mt - seg * 108) * 128;
  const int bb  = seg >> 1;
  const int g   = seg & 1;
  const int n0  = nt * 128;

  const int tid  = threadIdx.x;
  const int wv   = tid >> 6;
  const int lane = tid & 63;
  const int wr   = wv >> 1;    // wave row (m)
  const int wc   = wv & 1;     // wave col (n)
  const int lm   = lane & 15;
  const int quad = lane >> 4;

  // --- A staging role: thread owns rows rg*4..rg*4+3 at k-octet oc ---
  const int rg = tid >> 3;     // 0..31
  const int oc = tid & 7;      // 0..7
  const int jp = oc >> 2;      // j within k-tile (0..1)
  const int cb = (oc & 3) * 8; // channel base of the octet
  // x base for this thread (t_src*QQ added per kt)
  const float* xbase = x + ((size_t)bb * 32 + cb) * NSPAT + q0 + rg * 4;
  // swizzled LDS write offsets (shorts), rows rg*4+r
  int awof[4];
#pragma unroll
  for (int r = 0; r < 4; r++) {
    const int row = rg * 4 + r;
    awof[r] = row * 64 + ((oc * 8) ^ ((row & 7) << 3));
  }

  // --- B staging: wave wv copies tile shorts [wv*2048, +2048) linearly ---
  const short* bT = Bw + (size_t)nt * 16 * TS + wv * 2048 + lane * 8;
  short* bL = Bs + wv * 2048;

  // fragment read swizzle (row&7 == lm&7 since 16 | row-lm)
  const int rsw = (lm & 7) << 3;

  f32x4 acc[4][4];
#pragma unroll
  for (int i = 0; i < 4; i++)
#pragma unroll
    for (int jj = 0; jj < 4; jj++) {
      f32x4 z = {0.f, 0.f, 0.f, 0.f};
      acc[i][jj] = z;
    }

  for (int kt = 0; kt < 16; kt++) {
    // B: issue async copies first (independent VMEM)
#pragma unroll
    for (int is = 0; is < 4; is++)
      async16(bL + is * 512, bT + (size_t)kt * TS + is * 512);

    // A: 8 coalesced f32x4 plane loads -> cvt -> 4 swizzled b128 writes
    const int tsrc = ((g << 5) + (kt << 1) + jp + 48) & 63;
    const float* src = xbase + (size_t)tsrc * QQ;
    bf16x8 o[4];
#pragma unroll
    for (int tt = 0; tt < 8; tt++) {
      const f32x4 v = *(const f32x4*)(src + (size_t)tt * NSPAT);
#pragma unroll
      for (int r = 0; r < 4; r++) o[r][tt] = f2bf(v[r]);
    }
#pragma unroll
    for (int r = 0; r < 4; r++)
      *(bf16x8*)(As + awof[r]) = o[r];

    __syncthreads();  // drains vmcnt(0) (B copies) + lgkmcnt (A writes)

#pragma unroll
    for (int ks = 0; ks < 2; ks++) {
      bf16x8 af[4], bfr[4];
#pragma unroll
      for (int i = 0; i < 4; i++)
        af[i] = *(const bf16x8*)(As + (wr * 64 + i * 16 + lm) * 64
                                    + ((ks * 32 + quad * 8) ^ rsw));
#pragma unroll
      for (int jj = 0; jj < 4; jj++)
        bfr[jj] = *(const bf16x8*)(Bs + (wc * 64 + jj * 16 + lm) * 64
                                      + ((ks * 32 + quad * 8) ^ rsw));
#pragma unroll
      for (int i = 0; i < 4; i++)
#pragma unroll
        for (int jj = 0; jj < 4; jj++)
          acc[i][jj] = __builtin_amdgcn_mfma_f32_16x16x32_bf16(af[i], bfr[jj], acc[i][jj], 0, 0, 0);
    }
    __syncthreads();
  }

  // Epilogue: D row (quad*4+r) -> q (contiguous), col (lm) -> o; scatter by o
  float* ob = out + (size_t)bb * 32 * NSPAT;
#pragma unroll
  for (int jj = 0; jj < 4; jj++) {
    const int o  = n0 + wc * 64 + jj * 16 + lm;
    const float bv = bias[o];
    const int so = o >> 5;
    const int cc = o & 31;
    const int tt = ((g << 5) + so + 48) & 63;
    float* orow = ob + (size_t)cc * NSPAT + (size_t)tt * QQ + q0;
#pragma unroll
    for (int i = 0; i < 4; i++) {
      const int mb = wr * 64 + i * 16 + quad * 4;
      f32x4 v = acc[i][jj];
      v += bv;
      *(f32x4*)(orow + mb) = v;  // 16B-aligned
    }
  }
}

// ---------------------------------------------------------------------------
// Fallback (round-0 verified kernel) in case ws is too small (needs 2 MB).
// ---------------------------------------------------------------------------
__global__ __launch_bounds__(256, 2)
void swin_gemm(const float* __restrict__ x, const float* __restrict__ Wm,
               const float* __restrict__ bias, float* __restrict__ out) {
  const int bid = blockIdx.x;
  const int nt  = bid & 7;
  const int mt  = bid >> 3;
  const int seg = mt / 108;
  const int q0  = (mt - seg * 108) * 128;
  const int bb  = seg >> 1;
  const int g   = seg & 1;

  const int tid  = threadIdx.x;
  const int wv   = tid >> 6;
  const int wr   = wv >> 1;
  const int wc   = wv & 1;
  const int lane = tid & 63;
  const int lm   = lane & 15;
  const int quad = lane >> 4;

  const int n0 = nt * 128 + wc * 64;

  int aoff[4];
#pragma unroll
  for (int i = 0; i < 4; i++)
    aoff[i] = (quad * 8) * NSPAT + q0 + wr * 64 + i * 16 + lm;

  const float* wptr[4];
#pragma unroll
  for (int j = 0; j < 4; j++)
    wptr[j] = Wm + (size_t)(n0 + j * 16 + lm) * 1024 + quad * 8;

  f32x4 acc[4][4];
#pragma unroll
  for (int i = 0; i < 4; i++)
#pragma unroll
    for (int j = 0; j < 4; j++) {
      f32x4 z = {0.f, 0.f, 0.f, 0.f};
      acc[i][j] = z;
    }

  const float* xb = x + (size_t)bb * 32 * NSPAT;

  for (int kc = 0; kc < 32; kc++) {
    const int t_src = ((g << 5) + kc + 48) & 63;
    const float* xs = xb + (size_t)t_src * QQ;

    bf16x8 af[4];
#pragma unroll
    for (int i = 0; i < 4; i++) {
      float v[8];
#pragma unroll
      for (int t = 0; t < 8; t++)
        v[t] = xs[aoff[i] + t * NSPAT];
      bf16x8 f;
#pragma unroll
      for (int t = 0; t < 8; t++) f[t] = f2bf(v[t]);
      af[i] = f;
    }

    bf16x8 bfr[4];
#pragma unroll
    for (int j = 0; j < 4; j++) {
      const float* wp = wptr[j] + kc * 32;
      const f32x4 w0 = *(const f32x4*)(wp);
      const f32x4 w1 = *(const f32x4*)(wp + 4);
      bf16x8 f;
#pragma unroll
      for (int t = 0; t < 4; t++) { f[t] = f2bf(w0[t]); f[t + 4] = f2bf(w1[t]); }
      bfr[j] = f;
    }

#pragma unroll
    for (int i = 0; i < 4; i++)
#pragma unroll
      for (int j = 0; j < 4; j++)
        acc[i][j] = __builtin_amdgcn_mfma_f32_16x16x32_bf16(af[i], bfr[j], acc[i][j], 0, 0, 0);
  }

  float* ob = out + (size_t)bb * 32 * NSPAT;
#pragma unroll
  for (int j = 0; j < 4; j++) {
    const int o  = n0 + j * 16 + lm;
    const float bv = bias[o];
    const int so = o >> 5;
    const int cc = o & 31;
    const int tt = ((g << 5) + so + 48) & 63;
    float* orow = ob + (size_t)cc * NSPAT + (size_t)tt * QQ + q0;
#pragma unroll
    for (int i = 0; i < 4; i++) {
      const int mb = wr * 64 + i * 16 + quad * 4;
      f32x4 v = acc[i][j];
      v += bv;
      *(f32x4*)(orow + mb) = v;
    }
  }
}

extern "C" void kernel_launch(void* const* d_in, const int* in_sizes, int n_in,
                              void* d_out, int out_size, void* d_ws, size_t ws_size,
                              hipStream_t stream) {
  const float* x    = (const float*)d_in[0];
  const float* Wm   = (const float*)d_in[1];
  const float* bias = (const float*)d_in[2];
  float* out        = (float*)d_out;

  const size_t need = (size_t)KK * KK * 2;  // 2 MB for Wbf
  if (ws_size >= need) {
    short* Wbf = (short*)d_ws;
    convert_w<<<dim3(128), dim3(256), 0, stream>>>(Wm, Wbf);
    swin_fused<<<dim3(432 * 8), dim3(256), 0, stream>>>(x, Wbf, bias, out);
  } else {
    swin_gemm<<<dim3(432 * 8), dim3(256), 0, stream>>>(x, Wm, bias, out);
  }
}